// Round 1
// baseline (657.442 us; speedup 1.0000x reference)
//
#include <hip/hip_runtime.h>
#include <hip/hip_fp16.h>

typedef _Float16 h2  __attribute__((ext_vector_type(2)));
typedef _Float16 v8h __attribute__((ext_vector_type(8)));
typedef float    f4  __attribute__((ext_vector_type(4)));
typedef uint4 u128;

#define T_    20
#define C_    128
#define HW_   16384
#define NH_   16
#define TILE_ 16
#define EPSV  1e-5f

// workspace layout
#define OFF_SW   0        // SWh fp16 [16][128]   (score weights, gw folded)
#define OFF_SC   4096     // SC  f32  [2][20][16] (score constants, /2 folded)
#define OFF_WC   8192     // WCf fp16 [256][128]  (inconv_w * gw)
#define OFF_MW   73728    // MWf fp16 [128][256]  (mlp_w)
#define OFF_PBT  139264   // PBT fp16 [2][16][32] (PE table, e-major, t padded to 32)
#define OFF_MB2  141312   // MB2 f32  [128]       (mlp_b + BCfull @ mlp_w^T)

__device__ __forceinline__ float fdot2f(h2 a, h2 b, float c) {
#if __has_builtin(__builtin_amdgcn_fdot2)
  return __builtin_amdgcn_fdot2(a, b, c, false);
#else
  return c + (float)a[0]*(float)b[0] + (float)a[1]*(float)b[1];
#endif
}

__device__ __forceinline__ v8h zero8() {
  v8h r;
  #pragma unroll
  for (int i = 0; i < 8; ++i) r[i] = (_Float16)0.f;
  return r;
}

// ------------------------------ prep ------------------------------
__global__ void __launch_bounds__(256) ltae_prep(
    const int* __restrict__ bp, const float* __restrict__ gw, const float* __restrict__ gb,
    const float* __restrict__ icw, const float* __restrict__ icb,
    const float* __restrict__ Qm, const float* __restrict__ kw, const float* __restrict__ kb,
    const float* __restrict__ mw, const float* __restrict__ mb,
    unsigned char* __restrict__ ws)
{
  const int tid = threadIdx.x;
  const int blk = blockIdx.x;
  _Float16* SWh = (_Float16*)(ws + OFF_SW);
  float*    SC  = (float*)(ws + OFF_SC);
  _Float16* WCf = (_Float16*)(ws + OFF_WC);
  _Float16* MWf = (_Float16*)(ws + OFF_MW);
  _Float16* PBT = (_Float16*)(ws + OFF_PBT);
  float*    MB2 = (float*)(ws + OFF_MB2);

  __shared__ float qwl[16*256];
  __shared__ float bcl[256];
  __shared__ float pet[2*20*16];
  __shared__ float qbl[16];
  __shared__ float qwsl[16*16];

  if (blk < 4) {
    // SWh[h][c] = gw[c] * sum_d icw[d][c] * q_w[h][d]
    for (int o = tid; o < 512; o += 256) {
      int h = 4*blk + (o >> 7), c = o & 127;
      float q0 = Qm[h*4+0], q1 = Qm[h*4+1], q2 = Qm[h*4+2], q3 = Qm[h*4+3];
      const float* k0 = kw + (4*h+0)*256;
      const float* k1 = kw + (4*h+1)*256;
      const float* k2 = kw + (4*h+2)*256;
      const float* k3 = kw + (4*h+3)*256;
      float acc = 0.f;
      for (int d = 0; d < 256; ++d) {
        float qwd = k0[d]*q0 + k1[d]*q1 + k2[d]*q2 + k3[d]*q3;
        acc = fmaf(icw[d*128 + c], qwd, acc);
      }
      SWh[h*128 + c] = (_Float16)(acc * gw[c]);
    }
  } else if (blk < 6) {
    int base = (blk - 4) * 16384;
    for (int o = tid; o < 16384; o += 256) {
      int idx = base + o;
      WCf[idx] = (_Float16)(icw[idx] * gw[idx & 127]);
    }
  } else if (blk < 8) {
    int base = (blk - 6) * 16384;
    for (int o = tid; o < 16384; o += 256)
      MWf[base + o] = (_Float16)mw[base + o];
  } else if (blk == 8) {
    // MB2[j] = mlp_b[j] + sum_d BCfull[d]*mlp_w[j][d];  BCfull[d] = icb[d] + sum_c gb[c]*icw[d][c]
    if (tid < 256) {
      float a = icb[tid];
      for (int c2 = 0; c2 < 128; ++c2) a = fmaf(gb[c2], icw[tid*128 + c2], a);
      bcl[tid] = a;
    }
    __syncthreads();
    if (tid < 128) {
      float a = mb[tid];
      for (int d = 0; d < 256; ++d) a = fmaf(bcl[d], mw[tid*256 + d], a);
      MB2[tid] = a;
    }
  } else {
    // SC + PBT
    for (int o = tid; o < 4096; o += 256) {
      int h = o >> 8, d = o & 255;
      qwl[o] = kw[(4*h+0)*256+d]*Qm[h*4+0] + kw[(4*h+1)*256+d]*Qm[h*4+1]
             + kw[(4*h+2)*256+d]*Qm[h*4+2] + kw[(4*h+3)*256+d]*Qm[h*4+3];
    }
    if (tid < 256) {
      float a = icb[tid];
      for (int c2 = 0; c2 < 128; ++c2) a = fmaf(gb[c2], icw[tid*128 + c2], a);
      bcl[tid] = a;
    }
    for (int o = tid; o < 640; o += 256) {
      int bb = o / 320, rem = o % 320;
      int t = rem >> 4, e = rem & 15;
      float pos = (float)bp[bb*T_ + t];
      float den = powf(1000.f, (float)(2*(e>>1)) / 16.f);
      float v = pos / den;
      pet[o] = (e & 1) ? cosf(v) : sinf(v);
    }
    __syncthreads();
    if (tid < 16) {
      qbl[tid] = kb[tid*4+0]*Qm[tid*4+0] + kb[tid*4+1]*Qm[tid*4+1]
               + kb[tid*4+2]*Qm[tid*4+2] + kb[tid*4+3]*Qm[tid*4+3];
    }
    if (tid < 256) {
      int h = tid >> 4, e = tid & 15;
      float a = 0.f;
      for (int m2 = 0; m2 < 16; ++m2) a += qwl[h*256 + m2*16 + e];
      qwsl[tid] = a;
    }
    __syncthreads();
    for (int o = tid; o < 640; o += 256) {
      int bb = o / 320, rem = o % 320;
      int t = rem >> 4, h = rem & 15;
      float a = qbl[h];
      for (int d = 0; d < 256; ++d) a = fmaf(bcl[d], qwl[h*256 + d], a);
      for (int e = 0; e < 16; ++e) a = fmaf(pet[(bb*T_ + t)*16 + e], qwsl[h*16 + e], a);
      SC[(bb*T_ + t)*NH_ + h] = 0.5f * a;
    }
    for (int o = tid; o < 1024; o += 256) {
      int bb = o >> 9, e = (o >> 5) & 15, tp = o & 31;
      PBT[o] = (tp < T_) ? (_Float16)pet[(bb*T_ + tp)*16 + e] : (_Float16)0.f;
    }
  }
}

// ------------------------------ main ------------------------------
// block = 16 samples (consecutive n), 256 threads: thread (s = tid>>4, q = tid&15)
__global__ void __launch_bounds__(256, 2) ltae_main(
    const float* __restrict__ x, const unsigned char* __restrict__ ws,
    float* __restrict__ out,
    const float* __restrict__ lnw, const float* __restrict__ lnb,
    const float* __restrict__ onw, const float* __restrict__ onb)
{
  __shared__ __align__(16) unsigned char lds[81920]; // xs fp16 [20][16][128], swizzled rows
  const int tid = threadIdx.x;
  const int s = tid >> 4, q = tid & 15;
  const int lane = tid & 63;

  int bid = (int)blockIdx.x;
  int L = (bid & 7) * 256 + (bid >> 3);       // XCD-aware swizzle (bijective, 2048%8==0)
  const int n0 = L * TILE_;
  const int b  = n0 >> 14;
  const int r0 = n0 & 16383;

  // swizzled LDS addressing: row = 256B, chunk = 16B unit, chunk ^= (row&7)
  #define XS(row, chunk) ((unsigned char*)lds + (row)*256 + ((((chunk) ^ ((row)&7))) << 4))

  // ---------- P1: global -> stats + fp16 LDS stash ----------
  float gsum = 0.f, gsq = 0.f;
  {
    const float* p = x + (size_t)b*(T_*C_*HW_) + (size_t)(q*8)*HW_ + r0 + s;
    for (int t = 0; t < T_; ++t) {
      float v[8];
      #pragma unroll
      for (int i = 0; i < 8; ++i) v[i] = p[(size_t)i*HW_];
      p += (size_t)C_*HW_;
      #pragma unroll
      for (int i = 0; i < 8; ++i) { gsum += v[i]; gsq = fmaf(v[i], v[i], gsq); }
      u128 pk; h2* ph = (h2*)&pk;
      #pragma unroll
      for (int i = 0; i < 4; ++i) { h2 t2; t2[0] = (_Float16)v[2*i]; t2[1] = (_Float16)v[2*i+1]; ph[i] = t2; }
      *(u128*)XS(t*16 + s, q) = pk;
    }
  }
  // group stats: thread (s,q) owns group q of sample s; broadcast via shuffles
  float mug[16], invg[16];
  {
    float mu  = gsum * (1.f/160.f);
    float var = fmaf(-mu, mu, gsq * (1.f/160.f));
    float inv = rsqrtf(var + EPSV);
    int lb = lane & 48;
    #pragma unroll
    for (int g = 0; g < 16; ++g) {
      mug[g]  = __shfl(mu,  lb + g, 64);
      invg[g] = __shfl(inv, lb + g, 64);
    }
  }
  __syncthreads();

  // ---------- P2: scores for head q ----------
  float a_[T_];
  {
    h2 sw[64];
    {
      const u128* sp = (const u128*)(ws + OFF_SW) + q*16;
      #pragma unroll
      for (int i = 0; i < 16; ++i) ((u128*)sw)[i] = sp[i];
    }
    float K0 = 0.f;
    #pragma unroll
    for (int g = 0; g < 16; ++g) {
      float ss = 0.f;
      #pragma unroll
      for (int k = 0; k < 4; ++k) ss += (float)sw[g*4+k][0] + (float)sw[g*4+k][1];
      K0 = fmaf(invg[g]*mug[g], ss, K0);
    }
    const float* SCp = (const float*)(ws + OFF_SC) + (b*T_)*NH_ + q;
    #pragma unroll
    for (int t = 0; t < T_; ++t) {
      int row = t*16 + s;
      float accE = 0.f, accO = 0.f;
      #pragma unroll
      for (int g = 0; g < 16; g += 2) {
        u128 u0 = *(const u128*)XS(row, g);
        u128 u1 = *(const u128*)XS(row, g+1);
        h2* x0 = (h2*)&u0; h2* x1 = (h2*)&u1;
        float s0 = 0.f, s1 = 0.f;
        #pragma unroll
        for (int k = 0; k < 4; ++k) {
          s0 = fdot2f(x0[k], sw[g*4+k],     s0);
          s1 = fdot2f(x1[k], sw[(g+1)*4+k], s1);
        }
        accE = fmaf(invg[g],   s0, accE);
        accO = fmaf(invg[g+1], s1, accO);
      }
      a_[t] = 0.5f*((accE + accO) - K0) + SCp[t*NH_];
    }
  }
  // softmax (fully per-thread, exact f32)
  h2 ah[T_];
  {
    float m = a_[0];
    #pragma unroll
    for (int t = 1; t < T_; ++t) m = fmaxf(m, a_[t]);
    float Z = 0.f;
    #pragma unroll
    for (int t = 0; t < T_; ++t) { a_[t] = __expf(a_[t] - m); Z += a_[t]; }
    float rZ = 1.f / Z;
    #pragma unroll
    for (int t = 0; t < T_; ++t) {
      a_[t] *= rZ;
      _Float16 af = (_Float16)a_[t];
      h2 t2; t2[0] = af; t2[1] = af; ah[t] = t2;
    }
  }

  // ---------- P3a: ep[h=q][c] = sum_t attn*e', written IN-PLACE over xs ----------
  #pragma unroll 1
  for (int g = 0; g < 16; ++g) {
    h2 accA[4], accB[4];
    #pragma unroll
    for (int k = 0; k < 4; ++k) { accA[k][0]=(_Float16)0.f; accA[k][1]=(_Float16)0.f;
                                  accB[k][0]=(_Float16)0.f; accB[k][1]=(_Float16)0.f; }
    #pragma unroll
    for (int t = 0; t < T_; t += 2) {
      u128 u0 = *(const u128*)XS(t*16 + s, g);
      u128 u1 = *(const u128*)XS((t+1)*16 + s, g);
      h2* x0 = (h2*)&u0; h2* x1 = (h2*)&u1;
      #pragma unroll
      for (int k = 0; k < 4; ++k) {
        accA[k] = ah[t]  * x0[k] + accA[k];
        accB[k] = ah[t+1]* x1[k] + accB[k];
      }
    }
    __syncthreads();   // all reads of chunk g done -> safe to overwrite chunk g
    u128 pk; h2* ph = (h2*)&pk;
    #pragma unroll
    for (int k = 0; k < 4; ++k) {
      float lo = (float)accA[k][0] + (float)accB[k][0];
      float hi = (float)accA[k][1] + (float)accB[k][1];
      lo = invg[g]*(lo - mug[g]);
      hi = invg[g]*(hi - mug[g]);
      h2 t2; t2[0] = (_Float16)lo; t2[1] = (_Float16)hi; ph[k] = t2;
    }
    *(u128*)XS(q*16 + s, g) = pk;   // epl row = head*16 + sample
  }

  // attn -> atl fp16 [16h][16s][24t] at bytes 65536.. (xs rows 16..19, now dead)
  {
    unsigned char* atl = lds + 65536 + (q*16 + s)*48;
    u128 pk0, pk1, pk2;
    h2* p0 = (h2*)&pk0; h2* p1 = (h2*)&pk1; h2* p2 = (h2*)&pk2;
    #pragma unroll
    for (int k = 0; k < 4; ++k) { h2 t2; t2[0]=(_Float16)a_[2*k];   t2[1]=(_Float16)a_[2*k+1]; p0[k]=t2; }
    #pragma unroll
    for (int k = 0; k < 4; ++k) { h2 t2; t2[0]=(_Float16)a_[8+2*k]; t2[1]=(_Float16)a_[9+2*k]; p1[k]=t2; }
    #pragma unroll
    for (int k = 0; k < 4; ++k) {
      h2 t2;
      t2[0] = (k<2) ? (_Float16)a_[16+2*k] : (_Float16)0.f;
      t2[1] = (k<2) ? (_Float16)a_[17+2*k] : (_Float16)0.f;
      p2[k]=t2;
    }
    *(u128*)(atl) = pk0; *(u128*)(atl+16) = pk1; *(u128*)(atl+32) = pk2;
  }
  __syncthreads();

  // ---------- P3b: pooled[s][d] via MFMA, K = 128 (ep x WCf) + 32 (attn x PE) ----------
  const int wid = tid >> 6;
  const int lr = lane & 15, lk = lane >> 4;
  f4 pacc[4];
  {
    const _Float16* WC  = (const _Float16*)(ws + OFF_WC);
    const _Float16* PBT = (const _Float16*)(ws + OFF_PBT);
    #pragma unroll
    for (int hh = 0; hh < 4; ++hh) {
      int h = wid*4 + hh;
      f4 acc = {0.f,0.f,0.f,0.f};
      #pragma unroll
      for (int ks = 0; ks < 4; ++ks) {
        v8h A = *(const v8h*)XS(h*16 + lr, ks*4 + lk);                       // ep[s=lr][c]
        v8h B = *(const v8h*)(WC + (16*h + lr)*128 + ks*32 + lk*8);          // WCf[d=16h+lr][c]
        acc = __builtin_amdgcn_mfma_f32_16x16x32_f16(A, B, acc, 0, 0, 0);
      }
      { // PE pooling k-step
        v8h A = zero8();
        if (lk < 3) A = *(const v8h*)(lds + 65536 + (h*16 + lr)*48 + lk*16); // attn[s=lr][t']
        v8h B = *(const v8h*)(PBT + (b*16 + lr)*32 + lk*8);                  // PE[e'=lr][t']
        acc = __builtin_amdgcn_mfma_f32_16x16x32_f16(A, B, acc, 0, 0, 0);
      }
      pacc[hh] = acc;
    }
  }
  __syncthreads();   // all epl/atl reads done -> region 0..16383 reusable
  // plds fp16 [16][256] at offset 0 (swizzled rows)
  #pragma unroll
  for (int hh = 0; hh < 4; ++hh) {
    int d = 16*(wid*4 + hh) + lr;
    #pragma unroll
    for (int r = 0; r < 4; ++r) {
      int sp = 4*lk + r;
      *(_Float16*)(lds + ((sp*512 + d*2) ^ ((sp&7)<<4))) = (_Float16)pacc[hh][r];
    }
  }
  __syncthreads();

  // ---------- MLP: h1[s][j] via MFMA (wave w owns j in [32w, 32w+32)) ----------
  f4 m0 = {0.f,0.f,0.f,0.f}, m1 = {0.f,0.f,0.f,0.f};
  {
    const _Float16* MW = (const _Float16*)(ws + OFF_MW);
    #pragma unroll
    for (int ks = 0; ks < 8; ++ks) {
      int d0 = ks*32 + lk*8;
      v8h A  = *(const v8h*)(lds + ((lr*512 + d0*2) ^ ((lr&7)<<4)));         // pooled[s=lr][d]
      v8h B0 = *(const v8h*)(MW + (32*wid + lr)*256 + d0);                   // mlp_w[j][d]
      v8h B1 = *(const v8h*)(MW + (32*wid + 16 + lr)*256 + d0);
      m0 = __builtin_amdgcn_mfma_f32_16x16x32_f16(A, B0, m0, 0,0,0);
      m1 = __builtin_amdgcn_mfma_f32_16x16x32_f16(A, B1, m1, 0,0,0);
    }
  }
  {
    const float* MB2 = (const float*)(ws + OFF_MB2);
    int j0 = 32*wid + lr, j1 = 32*wid + 16 + lr;
    float b0 = MB2[j0], b1 = MB2[j1];
    #pragma unroll
    for (int r = 0; r < 4; ++r) {
      int sp = 4*lk + r;
      *(float*)(lds + 8192 + ((sp*512 + j0*4) ^ ((sp&7)<<4))) = m0[r] + b0;  // h1l f32 [16][128]
      *(float*)(lds + 8192 + ((sp*512 + j1*4) ^ ((sp&7)<<4))) = m1[r] + b1;
    }
  }
  __syncthreads();

  // ---------- final: LN -> GELU -> out GroupNorm -> store ----------
  {
    float4 A0 = *(const float4*)(lds + 8192 + (((s*512 + q*32)      ) ^ ((s&7)<<4)));
    float4 A1 = *(const float4*)(lds + 8192 + (((s*512 + q*32 + 16) ) ^ ((s&7)<<4)));
    float h1v[8] = {A0.x,A0.y,A0.z,A0.w,A1.x,A1.y,A1.z,A1.w};
    float sum = 0.f, sq = 0.f;
    #pragma unroll
    for (int i = 0; i < 8; ++i) { sum += h1v[i]; sq = fmaf(h1v[i], h1v[i], sq); }
    #pragma unroll
    for (int d = 1; d < 16; d <<= 1) { sum += __shfl_xor(sum, d, 64); sq += __shfl_xor(sq, d, 64); }
    float mu1 = sum * (1.f/128.f);
    float vr1 = fmaf(-mu1, mu1, sq * (1.f/128.f));
    float is1 = rsqrtf(vr1 + EPSV);
    float4 lwa = *(const float4*)(lnw + 8*q), lwb = *(const float4*)(lnw + 8*q + 4);
    float4 lba = *(const float4*)(lnb + 8*q), lbb = *(const float4*)(lnb + 8*q + 4);
    float lw[8] = {lwa.x,lwa.y,lwa.z,lwa.w,lwb.x,lwb.y,lwb.z,lwb.w};
    float lb2[8] = {lba.x,lba.y,lba.z,lba.w,lbb.x,lbb.y,lbb.z,lbb.w};
    float yv[8]; float s2 = 0.f, q2 = 0.f;
    #pragma unroll
    for (int i = 0; i < 8; ++i) {
      float g_ = (h1v[i]-mu1)*is1*lw[i] + lb2[i];
      float y  = 0.5f*g_*(1.f + erff(g_*0.70710678118654752f));
      yv[i] = y; s2 += y; q2 = fmaf(y, y, q2);
    }
    s2 *= 0.125f;
    float v2 = fmaf(-s2, s2, q2*0.125f);
    float iv2 = rsqrtf(v2 + EPSV);
    float4 owa = *(const float4*)(onw + 8*q), owb = *(const float4*)(onw + 8*q + 4);
    float4 oba = *(const float4*)(onb + 8*q), obb = *(const float4*)(onb + 8*q + 4);
    float ow[8] = {owa.x,owa.y,owa.z,owa.w,owb.x,owb.y,owb.z,owb.w};
    float ob[8] = {oba.x,oba.y,oba.z,oba.w,obb.x,obb.y,obb.z,obb.w};
    float* op = out + (size_t)(b*128 + 8*q)*HW_ + r0 + s;
    #pragma unroll
    for (int i = 0; i < 8; ++i)
      op[(size_t)i*HW_] = (yv[i]-s2)*iv2*ow[i] + ob[i];
  }
  #undef XS
}

extern "C" void kernel_launch(void* const* d_in, const int* in_sizes, int n_in,
                              void* d_out, int out_size, void* d_ws, size_t ws_size,
                              hipStream_t stream) {
  const float* x   = (const float*)d_in[0];
  const int*   bp  = (const int*)d_in[1];
  const float* gw  = (const float*)d_in[2];
  const float* gb  = (const float*)d_in[3];
  const float* icw = (const float*)d_in[4];
  const float* icb = (const float*)d_in[5];
  const float* Qm  = (const float*)d_in[6];
  const float* kw  = (const float*)d_in[7];
  const float* kb  = (const float*)d_in[8];
  const float* mw  = (const float*)d_in[9];
  const float* mb  = (const float*)d_in[10];
  const float* lnw = (const float*)d_in[11];
  const float* lnb = (const float*)d_in[12];
  const float* onw = (const float*)d_in[13];
  const float* onb = (const float*)d_in[14];
  unsigned char* ws = (unsigned char*)d_ws;

  hipLaunchKernelGGL(ltae_prep, dim3(10), dim3(256), 0, stream,
                     bp, gw, gb, icw, icb, Qm, kw, kb, mw, mb, ws);
  hipLaunchKernelGGL(ltae_main, dim3(2048), dim3(256), 0, stream,
                     x, ws, (float*)d_out, lnw, lnb, onw, onb);
}

// Round 5
// 603.269 us; speedup vs baseline: 1.0898x; 1.0898x over previous
//
#include <hip/hip_runtime.h>
#include <hip/hip_fp16.h>

typedef _Float16 h2  __attribute__((ext_vector_type(2)));
typedef _Float16 v8h __attribute__((ext_vector_type(8)));
typedef float    f4  __attribute__((ext_vector_type(4)));
typedef uint4 u128;

#define T_    20
#define C_    128
#define HW_   16384
#define NH_   16
#define TILE_ 16
#define EPSV  1e-5f

// workspace layout
#define OFF_SW   0        // SWh fp16 [16][128]   (score weights, gw AND 0.5/sqrt(d_k) folded)
#define OFF_SC   4096     // SC  f32  [2][20][16] (score constants, /2 folded)
#define OFF_WC   8192     // WCf fp16 [256][128]  (inconv_w * gw)
#define OFF_MW   73728    // MWf fp16 [128][256]  (mlp_w)
#define OFF_PBT  139264   // PBT fp16 [2][16][32] (PE table, e-major, t padded to 32)
#define OFF_MB2  141312   // MB2 f32  [128]       (mlp_b + BCfull @ mlp_w^T)

__device__ __forceinline__ v8h zero8() {
  v8h r;
  #pragma unroll
  for (int i = 0; i < 8; ++i) r[i] = (_Float16)0.f;
  return r;
}
__device__ __forceinline__ int h2i(h2 v) { union { h2 h; int i; } u; u.h = v; return u.i; }
__device__ __forceinline__ h2  ih2(int v) { union { h2 h; int i; } u; u.i = v; return u.h; }

// ------------------------------ prep ------------------------------
__global__ void __launch_bounds__(256) ltae_prep(
    const int* __restrict__ bp, const float* __restrict__ gw, const float* __restrict__ gb,
    const float* __restrict__ icw, const float* __restrict__ icb,
    const float* __restrict__ Qm, const float* __restrict__ kw, const float* __restrict__ kb,
    const float* __restrict__ mw, const float* __restrict__ mb,
    unsigned char* __restrict__ ws)
{
  const int tid = threadIdx.x;
  const int blk = blockIdx.x;
  _Float16* SWh = (_Float16*)(ws + OFF_SW);
  float*    SC  = (float*)(ws + OFF_SC);
  _Float16* WCf = (_Float16*)(ws + OFF_WC);
  _Float16* MWf = (_Float16*)(ws + OFF_MW);
  _Float16* PBT = (_Float16*)(ws + OFF_PBT);
  float*    MB2 = (float*)(ws + OFF_MB2);

  __shared__ float qwl[16*256];
  __shared__ float bcl[256];
  __shared__ float pet[2*20*16];
  __shared__ float qbl[16];
  __shared__ float qwsl[16*16];
  __shared__ float red[256];

  if (blk < 16) {
    // SWh[h][c] = 0.5 * gw[c] * sum_d icw[d][c] * q_w[h][d]   (0.5 = 1/sqrt(d_k) folded)
    int h = blk, dh = tid >> 7;
    float q0 = Qm[h*4+0], q1 = Qm[h*4+1], q2 = Qm[h*4+2], q3 = Qm[h*4+3];
    const float* k0 = kw + (4*h+0)*256;
    const float* k1 = kw + (4*h+1)*256;
    const float* k2 = kw + (4*h+2)*256;
    const float* k3 = kw + (4*h+3)*256;
    int c = tid & 127;
    float acc = 0.f;
    for (int d = 0; d < 128; ++d) {
      int dg = dh*128 + d;
      float qwd = k0[dg]*q0 + k1[dg]*q1 + k2[dg]*q2 + k3[dg]*q3;
      acc = fmaf(icw[dg*128 + c], qwd, acc);
    }
    red[tid] = acc;
    __syncthreads();
    if (tid < 128) SWh[h*128 + tid] = (_Float16)((red[tid] + red[tid+128]) * gw[tid] * 0.5f);
  } else if (blk < 18) {
    int base = (blk - 16) * 16384;
    for (int o = tid; o < 16384; o += 256) {
      int idx = base + o;
      WCf[idx] = (_Float16)(icw[idx] * gw[idx & 127]);
    }
  } else if (blk < 20) {
    int base = (blk - 18) * 16384;
    for (int o = tid; o < 16384; o += 256)
      MWf[base + o] = (_Float16)mw[base + o];
  } else if (blk == 20) {
    if (tid < 256) {
      float a = icb[tid];
      for (int c2 = 0; c2 < 128; ++c2) a = fmaf(gb[c2], icw[tid*128 + c2], a);
      bcl[tid] = a;
    }
    __syncthreads();
    if (tid < 128) {
      float a = mb[tid];
      for (int d = 0; d < 256; ++d) a = fmaf(bcl[d], mw[tid*256 + d], a);
      MB2[tid] = a;
    }
  } else {
    // SC + PBT
    for (int o = tid; o < 4096; o += 256) {
      int h = o >> 8, d = o & 255;
      qwl[o] = kw[(4*h+0)*256+d]*Qm[h*4+0] + kw[(4*h+1)*256+d]*Qm[h*4+1]
             + kw[(4*h+2)*256+d]*Qm[h*4+2] + kw[(4*h+3)*256+d]*Qm[h*4+3];
    }
    if (tid < 256) {
      float a = icb[tid];
      for (int c2 = 0; c2 < 128; ++c2) a = fmaf(gb[c2], icw[tid*128 + c2], a);
      bcl[tid] = a;
    }
    for (int o = tid; o < 640; o += 256) {
      int bb = o / 320, rem = o % 320;
      int t = rem >> 4, e = rem & 15;
      float pos = (float)bp[bb*T_ + t];
      float den = powf(1000.f, (float)(2*(e>>1)) / 16.f);
      float v = pos / den;
      pet[o] = (e & 1) ? cosf(v) : sinf(v);
    }
    __syncthreads();
    if (tid < 16) {
      qbl[tid] = kb[tid*4+0]*Qm[tid*4+0] + kb[tid*4+1]*Qm[tid*4+1]
               + kb[tid*4+2]*Qm[tid*4+2] + kb[tid*4+3]*Qm[tid*4+3];
    }
    if (tid < 256) {
      int h = tid >> 4, e = tid & 15;
      float a = 0.f;
      for (int m2 = 0; m2 < 16; ++m2) a += qwl[h*256 + m2*16 + e];
      qwsl[tid] = a;
    }
    __syncthreads();
    for (int o = tid; o < 640; o += 256) {
      int bb = o / 320, rem = o % 320;
      int t = rem >> 4, h = rem & 15;
      float a = qbl[h];
      for (int d = 0; d < 256; ++d) a = fmaf(bcl[d], qwl[h*256 + d], a);
      for (int e = 0; e < 16; ++e) a = fmaf(pet[(bb*T_ + t)*16 + e], qwsl[h*16 + e], a);
      SC[(bb*T_ + t)*NH_ + h] = 0.5f * a;
    }
    for (int o = tid; o < 1024; o += 256) {
      int bb = o >> 9, e = (o >> 5) & 15, tp = o & 31;
      PBT[o] = (tp < T_) ? (_Float16)pet[(bb*T_ + tp)*16 + e] : (_Float16)0.f;
    }
  }
}

// ------------------------------ main ------------------------------
// block = 16 samples, 512 threads (8 waves), e'' normalized fp16 in LDS
__global__ void __launch_bounds__(512, 4) ltae_main(
    const float* __restrict__ x, const unsigned char* __restrict__ ws,
    float* __restrict__ out,
    const float* __restrict__ lnw, const float* __restrict__ lnb,
    const float* __restrict__ onw, const float* __restrict__ onb)
{
  __shared__ __align__(16) unsigned char lds[81920]; // xs fp16 [20][16][128]
  const int tid  = threadIdx.x;
  const int lane = tid & 63;
  const int w    = tid >> 6;          // wave 0..7
  const int m16  = lane & 15, kg = lane >> 4;

  int bid = (int)blockIdx.x;
  int L = (bid & 7) * 256 + (bid >> 3);   // XCD swizzle (2048 % 8 == 0, bijective)
  const int n0 = L * TILE_;
  const int b  = n0 >> 14;
  const int r0 = n0 & 16383;

  // swizzled LDS addressing: row = 256B, 16 chunks of 16B; key varies with BOTH t/h and s
#define XS(row, chunk) ((unsigned char*)lds + (row)*256 + \
    ((((chunk) ^ (((row) ^ ((row) >> 4)) & 15))) << 4))
#define PL(s, byteo) ((unsigned char*)lds + (s)*512 + \
    (((((byteo) >> 4) ^ (((s)*2) & 31))) << 4) + ((byteo) & 15))
#define HL(s, byteo) ((unsigned char*)lds + 8192 + (s)*512 + \
    (((((byteo) >> 4) ^ (((s)*2) & 31))) << 4) + ((byteo) & 15))

  // ---------- P1: coalesced load, stats, normalize -> fp16 LDS ----------
  {
    const int sub = tid & 3, g = (tid >> 2) & 15, w8 = w;
    uint2 hp[20];
    float ps0=0,ps1=0,ps2=0,ps3=0, pq0=0,pq1=0,pq2=0,pq3=0;
    const float* xb = x + (size_t)b*(T_*C_*HW_) + r0 + 4*sub;
    #pragma unroll
    for (int k = 0; k < 20; ++k) {
      int j = w8 + 8*k;
      int t = j >> 3, cg = j & 7, c = g*8 + cg;
      float4 v = *(const float4*)(xb + (size_t)(t*C_ + c) * HW_);
      ps0 += v.x; pq0 = fmaf(v.x, v.x, pq0);
      ps1 += v.y; pq1 = fmaf(v.y, v.y, pq1);
      ps2 += v.z; pq2 = fmaf(v.z, v.z, pq2);
      ps3 += v.w; pq3 = fmaf(v.w, v.w, pq3);
      h2 lo; lo[0] = (_Float16)v.x; lo[1] = (_Float16)v.y;
      h2 hi; hi[0] = (_Float16)v.z; hi[1] = (_Float16)v.w;
      hp[k] = make_uint2((unsigned)h2i(lo), (unsigned)h2i(hi));
    }
    unsigned char* scr = (unsigned char*)lds + 65536; // rows 256..319, time-shared
    float psum[4] = {ps0,ps1,ps2,ps3}, psq[4] = {pq0,pq1,pq2,pq3};
    #pragma unroll
    for (int i = 0; i < 4; ++i) {
      int s = 4*sub + i;
      int word = w8*512 + g*32 + (((s + g) & 15) << 1);
      *(float2*)(scr + word*4) = make_float2(psum[i], psq[i]);
    }
    __syncthreads();
    float mu[4], inv[4];
    #pragma unroll
    for (int i = 0; i < 4; ++i) {
      int s = 4*sub + i;
      float su = 0.f, sq = 0.f;
      #pragma unroll
      for (int ww = 0; ww < 8; ++ww) {
        float2 p = *(const float2*)(scr + (ww*512 + g*32 + (((s + g) & 15) << 1))*4);
        su += p.x; sq += p.y;
      }
      float m_ = su * (1.f/160.f);
      mu[i]  = m_;
      inv[i] = rsqrtf(fmaf(-m_, m_, sq * (1.f/160.f)) + EPSV);
    }
#define P1WRITE(k) { \
      int j = w8 + 8*(k); \
      int t = j >> 3, cg = j & 7; \
      h2 lo = ih2((int)hp[k].x), hi = ih2((int)hp[k].y); \
      float f0 = ((float)lo[0] - mu[0]) * inv[0]; \
      float f1 = ((float)lo[1] - mu[1]) * inv[1]; \
      float f2 = ((float)hi[0] - mu[2]) * inv[2]; \
      float f3 = ((float)hi[1] - mu[3]) * inv[3]; \
      *(_Float16*)(XS(t*16 + 4*sub + 0, g) + cg*2) = (_Float16)f0; \
      *(_Float16*)(XS(t*16 + 4*sub + 1, g) + cg*2) = (_Float16)f1; \
      *(_Float16*)(XS(t*16 + 4*sub + 2, g) + cg*2) = (_Float16)f2; \
      *(_Float16*)(XS(t*16 + 4*sub + 3, g) + cg*2) = (_Float16)f3; }
    #pragma unroll
    for (int k = 0; k < 16; ++k) P1WRITE(k)
    __syncthreads();                 // all scratch reads done
    #pragma unroll
    for (int k = 16; k < 20; ++k) P1WRITE(k)
#undef P1WRITE
  }
  __syncthreads();

  // ---------- P2: scores via MFMA + softmax in D-layout ----------
  float attA[2][4], attB[2][4];
  {
    v8h Bsw[4];
    const _Float16* SWp = (const _Float16*)(ws + OFF_SW) + m16*128 + kg*8;
    #pragma unroll
    for (int ks = 0; ks < 4; ++ks) Bsw[ks] = *(const v8h*)(SWp + ks*32);
    const float* SCb = (const float*)(ws + OFF_SC) + b*T_*NH_;
    #pragma unroll
    for (int si = 0; si < 2; ++si) {
      int s = 2*w + si;
      f4 a0 = {0.f,0.f,0.f,0.f}, a1 = {0.f,0.f,0.f,0.f};
      #pragma unroll
      for (int ks = 0; ks < 4; ++ks) {
        v8h A = *(const v8h*)XS(m16*16 + s, ks*4 + kg);        // e''[t=m16][c]
        a0 = __builtin_amdgcn_mfma_f32_16x16x32_f16(A, Bsw[ks], a0, 0, 0, 0);
        v8h At = zero8();
        if (m16 < 4) At = *(const v8h*)XS((16 + m16)*16 + s, ks*4 + kg);
        a1 = __builtin_amdgcn_mfma_f32_16x16x32_f16(At, Bsw[ks], a1, 0, 0, 0);
      }
      float aa[4], ab[4] = {0.f,0.f,0.f,0.f};
      #pragma unroll
      for (int r = 0; r < 4; ++r) aa[r] = a0[r] + SCb[(4*kg + r)*NH_ + m16];
      if (kg == 0) {
        #pragma unroll
        for (int r = 0; r < 4; ++r) ab[r] = a1[r] + SCb[(16 + r)*NH_ + m16];
      }
      float mx = fmaxf(fmaxf(aa[0], aa[1]), fmaxf(aa[2], aa[3]));
      if (kg == 0) mx = fmaxf(mx, fmaxf(fmaxf(ab[0], ab[1]), fmaxf(ab[2], ab[3])));
      mx = fmaxf(mx, __shfl_xor(mx, 16, 64));
      mx = fmaxf(mx, __shfl_xor(mx, 32, 64));
      float Z = 0.f;
      #pragma unroll
      for (int r = 0; r < 4; ++r) { aa[r] = __expf(aa[r] - mx); Z += aa[r]; }
      if (kg == 0) {
        #pragma unroll
        for (int r = 0; r < 4; ++r) { ab[r] = __expf(ab[r] - mx); Z += ab[r]; }
      }
      Z += __shfl_xor(Z, 16, 64);
      Z += __shfl_xor(Z, 32, 64);
      float rZ = 1.f / Z;
      #pragma unroll
      for (int r = 0; r < 4; ++r) {
        attA[si][r] = aa[r] * rZ;
        attB[si][r] = (kg == 0) ? ab[r] * rZ : 0.f;
      }
    }
  }
  // attn packs: h2(sample0, sample1) so one shfl serves both halves
  int qi0,qi1,qi2,qi3, qb0,qb1,qb2,qb3;
  {
    h2 p;
    p[0]=(_Float16)attA[0][0]; p[1]=(_Float16)attA[1][0]; qi0=h2i(p);
    p[0]=(_Float16)attA[0][1]; p[1]=(_Float16)attA[1][1]; qi1=h2i(p);
    p[0]=(_Float16)attA[0][2]; p[1]=(_Float16)attA[1][2]; qi2=h2i(p);
    p[0]=(_Float16)attA[0][3]; p[1]=(_Float16)attA[1][3]; qi3=h2i(p);
    p[0]=(_Float16)attB[0][0]; p[1]=(_Float16)attB[1][0]; qb0=h2i(p);
    p[0]=(_Float16)attB[0][1]; p[1]=(_Float16)attB[1][1]; qb1=h2i(p);
    p[0]=(_Float16)attB[0][2]; p[1]=(_Float16)attB[1][2]; qb2=h2i(p);
    p[0]=(_Float16)attB[0][3]; p[1]=(_Float16)attB[1][3]; qb3=h2i(p);
  }

  // ---------- P3a: pooling, lane = (sample, 4 heads, 16 channels) ----------
  // two 10-term fp16 chains (even/odd t), combined in f32 at writeback
  const int sP = tid >> 5;                  // sample
  const int ll = lane & 31, hq = ll >> 3, cp = ll & 7;
  const int hiHalf = (lane >> 5) & 1;
  h2 acc0[4][8], acc1[4][8];
  #pragma unroll
  for (int i = 0; i < 4; ++i)
    #pragma unroll
    for (int c2 = 0; c2 < 8; ++c2) {
      acc0[i][c2][0] = (_Float16)0.f; acc0[i][c2][1] = (_Float16)0.f;
      acc1[i][c2][0] = (_Float16)0.f; acc1[i][c2][1] = (_Float16)0.f;
    }
  #pragma unroll
  for (int t = 0; t < T_; t += 2) {
    u128 u0 = *(const u128*)XS(t*16 + sP, 2*cp);
    u128 u1 = *(const u128*)XS(t*16 + sP, 2*cp + 1);
    u128 w0 = *(const u128*)XS((t+1)*16 + sP, 2*cp);
    u128 w1 = *(const u128*)XS((t+1)*16 + sP, 2*cp + 1);
    const h2* e0 = (const h2*)&u0; const h2* e1 = (const h2*)&u1;
    const h2* f0 = (const h2*)&w0; const h2* f1 = (const h2*)&w1;
    int qselE = (t < 16) ? (((t & 3) == 0) ? qi0 : qi2) : (((t & 3) == 0) ? qb0 : qb2);
    int qselO = (t < 16) ? (((t & 3) == 0) ? qi1 : qi3) : (((t & 3) == 0) ? qb1 : qb3);
    #pragma unroll
    for (int i = 0; i < 4; ++i) {
      int h = 4*hq + i;
      int src = (t < 16) ? (h + ((t >> 2) << 4)) : h;   // same for t and t+1 (t even)
      h2 pvE = ih2(__shfl(qselE, src, 64));
      h2 pvO = ih2(__shfl(qselO, src, 64));
      _Float16 aE = hiHalf ? pvE[1] : pvE[0];
      _Float16 aO = hiHalf ? pvO[1] : pvO[0];
      h2 aE2; aE2[0] = aE; aE2[1] = aE;
      h2 aO2; aO2[0] = aO; aO2[1] = aO;
      #pragma unroll
      for (int c2 = 0; c2 < 4; ++c2) {
        acc0[i][c2]     = aE2 * e0[c2] + acc0[i][c2];
        acc0[i][4 + c2] = aE2 * e1[c2] + acc0[i][4 + c2];
        acc1[i][c2]     = aO2 * f0[c2] + acc1[i][c2];
        acc1[i][4 + c2] = aO2 * f1[c2] + acc1[i][4 + c2];
      }
    }
  }
  __syncthreads();   // all e'' reads done -> xs reusable
  // ep[h][s][c] over rows 0..255 ; attn table + zero pad over rows 256..319
  #pragma unroll
  for (int i = 0; i < 4; ++i) {
    int h = 4*hq + i;
    u128 o0, o1;
    h2* p0 = (h2*)&o0; h2* p1 = (h2*)&o1;
    #pragma unroll
    for (int c2 = 0; c2 < 8; ++c2) {
      float lo = (float)acc0[i][c2][0] + (float)acc1[i][c2][0];
      float hi = (float)acc0[i][c2][1] + (float)acc1[i][c2][1];
      h2 t2; t2[0] = (_Float16)lo; t2[1] = (_Float16)hi;
      if (c2 < 4) p0[c2] = t2; else p1[c2 - 4] = t2;
    }
    *(u128*)XS(h*16 + sP, 2*cp)     = o0;
    *(u128*)XS(h*16 + sP, 2*cp + 1) = o1;
  }
  {
    unsigned char* atl = (unsigned char*)lds + 65536;  // [16h][16s][32t] fp16
    #pragma unroll
    for (int si = 0; si < 2; ++si) {
      int s = 2*w + si;
      #pragma unroll
      for (int r = 0; r < 4; ++r)
        *(_Float16*)(atl + (m16*16 + s)*64 + (4*kg + r)*2) = (_Float16)attA[si][r];
    }
    if (kg == 0) {
      #pragma unroll
      for (int si = 0; si < 2; ++si) {
        int s = 2*w + si;
        #pragma unroll
        for (int r = 0; r < 4; ++r)
          *(_Float16*)(atl + (m16*16 + s)*64 + (16 + r)*2) = (_Float16)attB[si][r];
      }
    }
    if (tid < 256) {   // zero t = 20..31
      unsigned char* zp = atl + tid*64 + 40;
      *(uint2*)(zp)      = make_uint2(0u, 0u);
      *(uint2*)(zp + 8)  = make_uint2(0u, 0u);
      *(uint2*)(zp + 16) = make_uint2(0u, 0u);
    }
  }
  __syncthreads();

  // ---------- P3b: pooled projection (K=128) + PE pooling (K=32) ----------
  f4 pacc[2];
  {
    const _Float16* WC  = (const _Float16*)(ws + OFF_WC);
    const _Float16* PBT = (const _Float16*)(ws + OFF_PBT);
    const unsigned char* atl = (const unsigned char*)lds + 65536;
    #pragma unroll
    for (int hh = 0; hh < 2; ++hh) {
      int hs = 2*w + hh;
      f4 a2 = {0.f,0.f,0.f,0.f};
      #pragma unroll
      for (int ks = 0; ks < 4; ++ks) {
        v8h A = *(const v8h*)XS(hs*16 + m16, ks*4 + kg);            // ep[s=m16][c]
        v8h B = *(const v8h*)(WC + (16*hs + m16)*128 + ks*32 + kg*8);
        a2 = __builtin_amdgcn_mfma_f32_16x16x32_f16(A, B, a2, 0, 0, 0);
      }
      v8h A2 = *(const v8h*)(atl + (hs*16 + m16)*64 + kg*16);       // attn[s=m16][t]
      v8h B2 = *(const v8h*)(PBT + (b*16 + m16)*32 + kg*8);         // PE[e'=m16][t]
      a2 = __builtin_amdgcn_mfma_f32_16x16x32_f16(A2, B2, a2, 0, 0, 0);
      pacc[hh] = a2;
    }
  }
  __syncthreads();   // ep/atl reads done -> low LDS reusable
  // plds fp16 [16s][256d] (swizzled), pair-packed via shfl
  #pragma unroll
  for (int hh = 0; hh < 2; ++hh) {
    int hs = 2*w + hh;
    int d = 16*hs + m16;
    #pragma unroll
    for (int r = 0; r < 4; ++r) {
      int other = __shfl_xor(__float_as_int(pacc[hh][r]), 1, 64);
      if ((m16 & 1) == 0) {
        h2 pk2; pk2[0] = (_Float16)pacc[hh][r]; pk2[1] = (_Float16)__int_as_float(other);
        *(int*)PL(4*kg + r, d*2) = h2i(pk2);
      }
    }
  }
  __syncthreads();

  // ---------- MLP via MFMA: wave w owns j in [16w, 16w+16) ----------
  {
    f4 macc = {0.f,0.f,0.f,0.f};
    const _Float16* MW = (const _Float16*)(ws + OFF_MW);
    #pragma unroll
    for (int ks = 0; ks < 8; ++ks) {
      v8h A = *(const v8h*)PL(m16, ks*64 + kg*16);                  // pooled[s=m16][d]
      v8h B = *(const v8h*)(MW + (16*w + m16)*256 + ks*32 + kg*8);  // mlp_w[j][d]
      macc = __builtin_amdgcn_mfma_f32_16x16x32_f16(A, B, macc, 0, 0, 0);
    }
    const float* MB2 = (const float*)(ws + OFF_MB2);
    int j = 16*w + m16;
    float bj = MB2[j];
    #pragma unroll
    for (int r = 0; r < 4; ++r)
      *(float*)HL(4*kg + r, j*4) = macc[r] + bj;                    // h1l f32 [16][128]
  }
  __syncthreads();

  // ---------- final: LN -> GELU -> out GroupNorm -> transposed store ----------
  {
    const int sF = tid >> 5, rF = tid & 31;        // 4 channels per thread
    float4 A0 = *(const float4*)HL(sF, rF*16);
    float h1v[4] = {A0.x, A0.y, A0.z, A0.w};
    float sum = 0.f, sq = 0.f;
    #pragma unroll
    for (int i = 0; i < 4; ++i) { sum += h1v[i]; sq = fmaf(h1v[i], h1v[i], sq); }
    #pragma unroll
    for (int d = 1; d < 32; d <<= 1) { sum += __shfl_xor(sum, d, 64); sq += __shfl_xor(sq, d, 64); }
    float mu1 = sum * (1.f/128.f);
    float vr1 = fmaf(-mu1, mu1, sq * (1.f/128.f));
    float is1 = rsqrtf(vr1 + EPSV);
    float4 lw4 = *(const float4*)(lnw + 4*rF);
    float4 lb4 = *(const float4*)(lnb + 4*rF);
    float lw[4] = {lw4.x, lw4.y, lw4.z, lw4.w};
    float lb2[4] = {lb4.x, lb4.y, lb4.z, lb4.w};
    float yv[4]; float ys = 0.f, yq = 0.f;
    #pragma unroll
    for (int i = 0; i < 4; ++i) {
      float g_ = (h1v[i] - mu1)*is1*lw[i] + lb2[i];
      float y  = 0.5f*g_*(1.f + erff(g_*0.70710678118654752f));
      yv[i] = y; ys += y; yq = fmaf(y, y, yq);
    }
    // GroupNorm: 8-channel groups = this thread + partner (rF^1)
    ys += __shfl_xor(ys, 1, 64);
    yq += __shfl_xor(yq, 1, 64);
    float m2  = ys * 0.125f;
    float v2  = fmaf(-m2, m2, yq * 0.125f);
    float iv2 = rsqrtf(v2 + EPSV);
    float4 ow4 = *(const float4*)(onw + 4*rF);
    float4 ob4 = *(const float4*)(onb + 4*rF);
    float ow[4] = {ow4.x, ow4.y, ow4.z, ow4.w};
    float ob[4] = {ob4.x, ob4.y, ob4.z, ob4.w};
    float4 yo;
    yo.x = (yv[0]-m2)*iv2*ow[0] + ob[0];
    yo.y = (yv[1]-m2)*iv2*ow[1] + ob[1];
    yo.z = (yv[2]-m2)*iv2*ow[2] + ob[2];
    yo.w = (yv[3]-m2)*iv2*ow[3] + ob[3];
    *(float4*)HL(sF, rF*16) = yo;      // writeback in place
  }
  __syncthreads();
  {
    // transposed store: thread (j, s-quad) -> float4 along W (64B lines)
    int jT = tid >> 2, sq4 = tid & 3;
    float4 o;
    o.x = *(const float*)HL(4*sq4 + 0, jT*4);
    o.y = *(const float*)HL(4*sq4 + 1, jT*4);
    o.z = *(const float*)HL(4*sq4 + 2, jT*4);
    o.w = *(const float*)HL(4*sq4 + 3, jT*4);
    *(float4*)(out + (size_t)(b*128 + jT)*HW_ + r0 + 4*sq4) = o;
  }
#undef XS
#undef PL
#undef HL
}

extern "C" void kernel_launch(void* const* d_in, const int* in_sizes, int n_in,
                              void* d_out, int out_size, void* d_ws, size_t ws_size,
                              hipStream_t stream) {
  const float* x   = (const float*)d_in[0];
  const int*   bp  = (const int*)d_in[1];
  const float* gw  = (const float*)d_in[2];
  const float* gb  = (const float*)d_in[3];
  const float* icw = (const float*)d_in[4];
  const float* icb = (const float*)d_in[5];
  const float* Qm  = (const float*)d_in[6];
  const float* kw  = (const float*)d_in[7];
  const float* kb  = (const float*)d_in[8];
  const float* mw  = (const float*)d_in[9];
  const float* mb  = (const float*)d_in[10];
  const float* lnw = (const float*)d_in[11];
  const float* lnb = (const float*)d_in[12];
  const float* onw = (const float*)d_in[13];
  const float* onb = (const float*)d_in[14];
  unsigned char* ws = (unsigned char*)d_ws;

  hipLaunchKernelGGL(ltae_prep, dim3(22), dim3(256), 0, stream,
                     bp, gw, gb, icw, icb, Qm, kw, kb, mw, mb, ws);
  hipLaunchKernelGGL(ltae_main, dim3(2048), dim3(512), 0, stream,
                     x, ws, (float*)d_out, lnw, lnb, onw, onb);
}